// Round 12
// baseline (180.874 us; speedup 1.0000x reference)
//
#include <hip/hip_runtime.h>
#include <math.h>
#include <stdint.h>

// ---------------------------------------------------------------------------
// v14 (resubmit; previous round hit container-infra failure, never benched):
// v13 + z-phase hoisted out of k_zF:
//  - k_z computes all 2560x715 z values ONCE (fp16-packed u32, 7.3 MB gZ),
//    coalesced writes. Same expression/inputs/pack as v12 -> bit-identical.
//  - k_F stages its 4 z-rows (2860 u32 = 11.4 KB) into LDS with dense
//    coalesced copies (11 iters, replaces fbl/yol/gPack staging + z compute),
//    then runs v12's quad-store F-phase unchanged. LDS 21.2 -> 11.4 KB.
// gemm2 (grid 800, whole-slice B LDS burst) unchanged from v13.
// Pipeline: setup_w -> setup_const -> fhat -> k_z -> k_F -> gemm2.
// ---------------------------------------------------------------------------

typedef _Float16 half8 __attribute__((ext_vector_type(8)));
typedef float    f32x4 __attribute__((ext_vector_type(4)));

// workspace float offsets
#define WS_W    128     // gW [k60][sm55]                 3300
#define WS_Y    17760   // gyhat [o5][s100][i2] float2
#define WS_EM   19776   // gEm [m10][j60] float2
#define WS_TRIG 20992   // 20 dbl sin + 20 dbl cos (ex-gRT region)
#define WS_PACK 21184   // gPack[715] int
#define WS_AP   21952   // A-pack 172032 fp16
#define WS_FH   107968  // gfhat [b512][sm55][i2] float2 = 112640 floats
#define WS_DT   220608  // gDT [p715][k20] = 14300 floats
#define WS_F    234908  // gF 9,830,400 dwords (39.3 MB) B-frag layout
#define WS_Z    10100000 // gZ [po2560][p715] u32 fp16-pair = 1,830,400 dwords

// setup idx ranges (non-overlapping)
#define IX_Y0    3300
#define IX_EM0   4300
#define IX_RT0   4900
#define IX_PACK0 5090
#define IX_AP0   5805
#define IX_DT0   177837   // IX_AP0 + 172032
#define N_SETUP  192137   // + 14300

__device__ __forceinline__ double ipow_d(double x, int e) {
    double r = 1.0;
    for (int i = 0; i < e; ++i) r *= x;
    return r;
}

__device__ double dsmall(int l, int mp, int m, double beta) {
    double fact[20];
    fact[0] = 1.0;
    for (int i = 1; i < 20; ++i) fact[i] = fact[i - 1] * (double)i;
    double cb = cos(0.5 * beta), sb = sin(0.5 * beta);
    double pref = sqrt(fact[l + m] * fact[l - m] * fact[l + mp] * fact[l - mp]);
    int s0 = m - mp; if (s0 < 0) s0 = 0;
    int s1 = l + m;  if (l - mp < s1) s1 = l - mp;
    double tot = 0.0;
    for (int s = s0; s <= s1; ++s) {
        double den = fact[l + m - s] * fact[s] * fact[mp - m + s] * fact[l - mp - s];
        double sgn = ((mp - m + s) & 1) ? -1.0 : 1.0;
        tot += sgn / den * ipow_d(cb, 2 * l + m - mp - 2 * s) * ipow_d(sb, mp - m + 2 * s);
    }
    return pref * tot;
}

extern "C" __global__ void k_setup_w(float* wsf) {
    double* w = (double*)wsf;
    int t = threadIdx.x;
    if (t < 60) {
        double beta = M_PI * (2 * t + 1) / 120.0;
        double sum = 0.0;
        for (int k = 0; k < 30; ++k)
            sum += sin((double)((2 * t + 1) * (2 * k + 1)) * M_PI / 120.0) / (double)(2 * k + 1);
        w[t] = (2.0 / 30.0) * sin(beta) * sum;
    }
    if (t < 20) {   // A-pack trig table: sin/cos(pi*t/10), exact same expr as original
        double ang = M_PI * (double)t / 10.0;
        ((double*)(wsf + WS_TRIG))[t]      = sin(ang);
        ((double*)(wsf + WS_TRIG))[20 + t] = cos(ang);
    }
}

extern "C" __global__ void k_setup_const(float* wsf, const float* __restrict__ kern) {
    const double* w = (const double*)wsf;
    const int tri[11] = {0, 1, 3, 6, 10, 15, 21, 28, 36, 45, 55};
    int idx = blockIdx.x * 64 + threadIdx.x;
    if (idx < IX_Y0) {                      // gW [k][sm]
        int k = idx / 55, smi = idx % 55;
        int l = 0; while (smi >= tri[l + 1]) ++l;
        int m = smi - tri[l];
        double beta = M_PI * (2 * k + 1) / 120.0;
        wsf[WS_W + idx] = (float)(w[k] * dsmall(l, m, 0, beta));
    } else if (idx < IX_EM0) {              // gyhat [o][s][i]
        int i3 = idx - IX_Y0;
        int o = i3 / 200, r5 = i3 % 200;
        int s = r5 / 2, i = r5 % 2;
        int l = 0; while ((l + 1) * (l + 1) <= s) ++l;
        int n = s - l * l - l;
        double dv = dsmall(l, n, 0, M_PI / 160.0);
        const double SC = 1.0 / sqrt(6.0 * 2.0 * 10000.0 / 900.0);
        double ar = 0.0, ai = 0.0;
        for (int g = 0; g < 6; ++g) {
            double kv = (double)kern[i * 30 + o * 6 + g];
            double ang = (double)n * M_PI * (double)g / 3.0;
            ar += kv * cos(ang);
            ai -= kv * sin(ang);
        }
        ((float2*)(wsf + WS_Y))[i3] = make_float2((float)(SC * dv * ar), (float)(SC * dv * ai));
    } else if (idx < IX_RT0) {              // gEm [m][j]
        int t = idx - IX_EM0; int m = t / 60, j = t % 60;
        double a = 2.0 * M_PI * (double)(m * j) / 60.0;
        ((float2*)(wsf + WS_EM))[t] = make_float2((float)cos(a), (float)(-sin(a)));
    } else if (idx < IX_PACK0) {
        // ex-gRT region holds the trig table (written by k_setup_w)
    } else if (idx < IX_AP0) {              // gPack[715]
        int p = idx - IX_PACK0;
        int l = 0, bcur = 0;
        for (;;) { int bs = (l + 1) * (2 * l + 1); if (p < bcur + bs) break; bcur += bs; ++l; }
        int r = p - bcur; int L = 2 * l + 1;
        int m = r / L; int n = r % L - l;
        int smi = tri[l] + m; int sf = l * l + l + n;
        ((int*)(wsf + WS_PACK))[p] = smi * 128 + sf;
    } else if (idx < IX_DT0) {              // A-pack (A-fragment lane order), table lookup
        int ap = idx - IX_AP0;
        int j = ap & 7, lane = (ap >> 3) & 63, tc = ap >> 9;
        int t = tc % 28, c = tc / 28;
        int pq = t * 16 + (lane & 15);
        int kidx = c * 32 + ((lane >> 4) << 3) + j;
        double val = 0.0;
        if (pq < 400 && kidx < 380) {
            int r = kidx >> 1, cpart = kidx & 1;
            int m = r / 19, nn = r % 19, n = nn - 9;
            int p = pq / 20, q = pq % 20;
            int th = ((m * p + n * q) % 20 + 20) % 20;
            double wm = m ? 2.0 : 1.0;
            const double* st = (const double*)(wsf + WS_TRIG);
            val = cpart ? (-wm * st[th]) : (wm * st[20 + th]);
        }
        ((_Float16*)(wsf + WS_AP))[ap] = (_Float16)val;
    } else if (idx < N_SETUP) {             // gDT [p][k] transposed
        int i6 = idx - IX_DT0;
        int p = i6 / 20, k = i6 % 20;
        int l = 0, bcur = 0;
        for (;;) { int bs = (l + 1) * (2 * l + 1); if (p < bcur + bs) break; bcur += bs; ++l; }
        int r = p - bcur; int L = 2 * l + 1;
        int m = r / L; int n = r % L - l;
        double beta = M_PI * (2 * k + 1) / 40.0;
        wsf[WS_DT + i6] = (float)((double)L * dsmall(l, m, n, beta));
    }
}

// ---- fhat: block per (b,i) ----
extern "C" __global__ void __launch_bounds__(256) k_fhat(const float* __restrict__ x,
                                                          float* __restrict__ wsf) {
    __shared__ float  xs[3600];
    __shared__ float2 ems[610];
    __shared__ float2 Y[600];
    int tid = threadIdx.x;
    int bi = blockIdx.x;
    const float4* xp = (const float4*)(x + bi * 3600);
    for (int t = tid; t < 900; t += 256) ((float4*)xs)[t] = xp[t];
    const float2* gEm = (const float2*)(wsf + WS_EM);
    for (int t = tid; t < 600; t += 256) {
        int m = t / 60, j = t - m * 60;
        ems[m * 61 + j] = gEm[t];
    }
    __syncthreads();
    for (int it = tid; it < 600; it += 256) {
        int k = it / 10, m = it - k * 10;
        const float*  row = xs + k * 60;
        const float2* em  = ems + m * 61;
        float ar = 0.f, ai = 0.f;
        #pragma unroll 12
        for (int j = 0; j < 60; ++j) {
            float xv = row[j];
            float2 e = em[j];
            ar += xv * e.x; ai += xv * e.y;
        }
        Y[it] = make_float2(ar, ai);
    }
    __syncthreads();
    if (tid < 55) {
        int smi = tid;
        const int tri[11] = {0, 1, 3, 6, 10, 15, 21, 28, 36, 45, 55};
        int l = 0; while (smi >= tri[l + 1]) ++l;
        int m = smi - tri[l];
        const float* gW = wsf + WS_W;
        float ar = 0.f, ai = 0.f;
        for (int kk = 0; kk < 60; ++kk) {
            float wv = gW[kk * 55 + smi];
            float2 y = Y[kk * 10 + m];
            ar += wv * y.x; ai += wv * y.y;
        }
        int b = bi >> 1, i = bi & 1;
        ((float2*)(wsf + WS_FH))[b * 110 + smi * 2 + i] = make_float2(ar, ai);
    }
}

// ---- k_z: one thread per (po,p) -> gZ[po][p] fp16-packed u32 ----
// Same f32 expression/inputs and pack as v12's in-block z-phase -> identical.
extern "C" __global__ void __launch_bounds__(256) k_z(float* __restrict__ wsf) {
    int idx = blockIdx.x * 256 + threadIdx.x;
    if (idx >= 2560 * 715) return;
    int po = idx / 715, p = idx - po * 715;
    int b = po / 5, o = po - b * 5;
    int pk = ((const int*)(wsf + WS_PACK))[p];
    int smi = pk >> 7, sf = pk & 127;
    float4 f = ((const float4*)(wsf + WS_FH))[b * 55 + smi];
    float4 y = ((const float4*)(wsf + WS_Y))[o * 100 + sf];
    float zr = f.x * y.x + f.y * y.y + f.z * y.z + f.w * y.w;
    float zi = f.y * y.x - f.x * y.y + f.w * y.z - f.z * y.w;
    union { _Float16 h[2]; uint32_t u; } cv;
    cv.h[0] = (_Float16)zr; cv.h[1] = (_Float16)zi;
    ((uint32_t*)(wsf + WS_Z))[idx] = cv.u;
}

// unrolled F-sum for compile-time lmin L: steps l = L..9, straight-line,
// all loads independent -> full MLP. z is fp16-packed in LDS.
template<int L>
__device__ __forceinline__ void fsum(int m, int n, int ko, const float* __restrict__ gDT,
                                     const uint32_t* zp, float& fr, float& fi) {
    const int baseL[10] = {0, 1, 7, 22, 50, 95, 161, 252, 372, 525};
    float dv[10 - L];
    uint32_t zv[10 - L];
    #pragma unroll
    for (int l = L; l < 10; ++l) {
        int p = baseL[l] + m * (2 * l + 1) + n + l;
        dv[l - L] = gDT[p * 20 + ko];
        zv[l - L] = zp[p];
    }
    #pragma unroll
    for (int l = L; l < 10; ++l) {
        union { uint32_t u; _Float16 h[2]; } zc; zc.u = zv[l - L];
        fr += dv[l - L] * (float)zc.h[0];
        fi += dv[l - L] * (float)zc.h[1];
    }
}

// ---- k_F: stage 4 z-rows (coalesced) -> LDS, then v12 quad-store F-phase ----
extern "C" __global__ void __launch_bounds__(256) k_F(float* __restrict__ wsf) {
    __shared__ uint32_t zsh[2860];    // z [pp4][p715] fp16-packed (11.4 KB)
    int tid = threadIdx.x;
    int half = blockIdx.x & 1;
    int nb   = blockIdx.x >> 1;
    int n0 = nb * 64;
    int PO0 = n0 / 20;

    // dense coalesced copy: zsh[pp*715+p] = gZ[(PO0+pp)*715+p]
    const uint32_t* gZ = ((const uint32_t*)(wsf + WS_Z)) + PO0 * 715;
    for (int t = tid; t < 2860; t += 256) zsh[t] = gZ[t];
    __syncthreads();

    int col = tid & 63;
    int ko  = (n0 + col) % 20;
    int pp  = ((n0 % 20) + col) / 20;
    int gg  = (n0 >> 4) + (col >> 4);
    int c15 = col & 15;
    const float* gDT = wsf + WS_DT;
    uint4*       gF4 = (uint4*)(wsf + WS_F);
    const uint32_t* zp = zsh + pp * 715;
    // 48 quads of r; even quads -> half 0, odd -> half 1; 24 quads x 64 cols
    for (int it = tid; it < 1536; it += 256) {
        int qj = __builtin_amdgcn_readfirstlane(((it >> 6) << 1) | half);  // quad 0..47
        uint32_t fq[4];
        #pragma unroll
        for (int rr = 0; rr < 4; ++rr) {
            int r = 4 * qj + rr;          // wave-uniform scalar
            float fr = 0.f, fi = 0.f;
            if (r < 190) {
                int m = r / 19;
                int n = r - m * 19 - 9;
                int a = n < 0 ? -n : n;
                int lmin = m > a ? m : a;
                switch (lmin) {
                    case 0: fsum<0>(m, n, ko, gDT, zp, fr, fi); break;
                    case 1: fsum<1>(m, n, ko, gDT, zp, fr, fi); break;
                    case 2: fsum<2>(m, n, ko, gDT, zp, fr, fi); break;
                    case 3: fsum<3>(m, n, ko, gDT, zp, fr, fi); break;
                    case 4: fsum<4>(m, n, ko, gDT, zp, fr, fi); break;
                    case 5: fsum<5>(m, n, ko, gDT, zp, fr, fi); break;
                    case 6: fsum<6>(m, n, ko, gDT, zp, fr, fi); break;
                    case 7: fsum<7>(m, n, ko, gDT, zp, fr, fi); break;
                    case 8: fsum<8>(m, n, ko, gDT, zp, fr, fi); break;
                    default: fsum<9>(m, n, ko, gDT, zp, fr, fi); break;
                }
            }
            union { _Float16 h[2]; uint32_t u; } fv;
            fv.h[0] = (_Float16)fr; fv.h[1] = (_Float16)fi;
            fq[rr] = fv.u;
        }
        // chunk = qj>>2, qp = qj&3; dwords 0..3 = r&3 -> one dense 16B store
        gF4[((qj >> 2) * 3200 + gg) * 64 + (qj & 3) * 16 + c15] =
            make_uint4(fq[0], fq[1], fq[2], fq[3]);
    }
}

// ---- k_gemm2: grid 800, whole 48KB B-slice LDS burst, v7 tile mapping ----
extern "C" __global__ void __launch_bounds__(256) k_gemm2(const float* __restrict__ wsf,
                                                           const float* __restrict__ bias,
                                                           float* __restrict__ out) {
    __shared__ __align__(16) _Float16 Bsh[12 * 4 * 64 * 8];   // 48 KB
    int tid = threadIdx.x;
    int n0 = blockIdx.x * 64;
    int wave = tid >> 6, lane = tid & 63;
    int g0 = n0 >> 4;
    const half8* gA = (const half8*)(wsf + WS_AP);
    const half8* gB = (const half8*)(wsf + WS_F);
    half8* lB = (half8*)Bsh;

    // ---- stage ALL B for this n0 into LDS: 12 frags/wave, loads batched ----
    half8 stg[12];
    #pragma unroll
    for (int i = 0; i < 12; ++i) {
        int cf = wave * 12 + i;                  // cf = c*4 + f, 0..47
        int c = cf >> 2, f = cf & 3;
        stg[i] = gB[(c * 3200 + g0 + f) * 64 + lane];
    }
    #pragma unroll
    for (int i = 0; i < 12; ++i)
        lB[(wave * 12 + i) * 64 + lane] = stg[i];

    int t0 = wave * 7;
    int ntile = (wave < 3) ? 7 : 4;          // tiles 21..24 real; 25..27 pad

    f32x4 acc[7][4];
    #pragma unroll
    for (int tt = 0; tt < 7; ++tt)
        #pragma unroll
        for (int f = 0; f < 4; ++f) acc[tt][f] = (f32x4){0.f, 0.f, 0.f, 0.f};

    half8 bufA[2][7];
    #pragma unroll
    for (int tt = 0; tt < 7; ++tt)
        if (tt < ntile) bufA[0][tt] = gA[(t0 + tt) * 64 + lane];

    __syncthreads();   // B resident in LDS

    #pragma unroll
    for (int c = 0; c < 12; ++c) {
        const int cur = c & 1, nxt = cur ^ 1;
        if (c < 11) {
            #pragma unroll
            for (int tt = 0; tt < 7; ++tt)
                if (tt < ntile) bufA[nxt][tt] = gA[((c + 1) * 28 + t0 + tt) * 64 + lane];
        }
        half8 bB[4];
        #pragma unroll
        for (int f = 0; f < 4; ++f) bB[f] = lB[(c * 4 + f) * 64 + lane];
        #pragma unroll
        for (int tt = 0; tt < 7; ++tt) {
            if (tt < ntile) {
                #pragma unroll
                for (int f = 0; f < 4; ++f)
                    acc[tt][f] = __builtin_amdgcn_mfma_f32_16x16x32_f16(bufA[cur][tt], bB[f], acc[tt][f], 0, 0, 0);
            }
        }
    }

    int quad4 = (lane >> 4) << 2, col15 = lane & 15;
    float bo_f[4];
    #pragma unroll
    for (int f = 0; f < 4; ++f) bo_f[f] = bias[((n0 + f * 16 + col15) / 20) % 5];
    #pragma unroll
    for (int tt = 0; tt < 7; ++tt) {
        if (tt < ntile) {
            int pqb = (t0 + tt) * 16 + quad4;
            #pragma unroll
            for (int f = 0; f < 4; ++f) {
                int n = n0 + f * 16 + col15;
                float bo = bo_f[f];
                float4 v = make_float4(acc[tt][f].x + bo, acc[tt][f].y + bo,
                                       acc[tt][f].z + bo, acc[tt][f].w + bo);
                *(float4*)(out + n * 400 + pqb) = v;
            }
        }
    }
}

extern "C" void kernel_launch(void* const* d_in, const int* in_sizes, int n_in,
                              void* d_out, int out_size, void* d_ws, size_t ws_size,
                              hipStream_t stream) {
    const float* x    = (const float*)d_in[0];
    const float* kern = (const float*)d_in[1];
    const float* bias = (const float*)d_in[2];
    float* out = (float*)d_out;
    float* wsf = (float*)d_ws;
    k_setup_w    <<<1,    64,  0, stream>>>(wsf);
    k_setup_const<<<3003, 64,  0, stream>>>(wsf, kern);
    k_fhat       <<<1024, 256, 0, stream>>>(x, wsf);
    k_z          <<<7150, 256, 0, stream>>>(wsf);
    k_F          <<<1600, 256, 0, stream>>>(wsf);
    k_gemm2      <<<800,  256, 0, stream>>>(wsf, bias, out);
}

// Round 14
// 177.552 us; speedup vs baseline: 1.0187x; 1.0187x over previous
//
#include <hip/hip_runtime.h>
#include <math.h>
#include <stdint.h>

// ---------------------------------------------------------------------------
// v15 (resubmit; previous round hit GPU-broker timeout, never benched):
// v13 (best, 174.3us) + k_zF z-phase reads f/y DIRECT from global
// (L1/L2-resident: yol is the same 8KB for all blocks; fbl 1.76KB/block)
// -> deletes the fbl/yol LDS staging pass AND the first barrier. Identical
// f32 values/expression -> bit-identical output. LDS 21.2 -> 11.4 KB.
// v14's z-hoist REVERTED (regressed +6.6us: separate k_z launch+drain cost
// more than the overlapped in-block z duplication it removed).
// gemm2 (grid 800, whole-slice B LDS burst) unchanged from v13.
// Pipeline: setup_w -> setup_const -> fhat -> zF -> gemm2.
// ---------------------------------------------------------------------------

typedef _Float16 half8 __attribute__((ext_vector_type(8)));
typedef float    f32x4 __attribute__((ext_vector_type(4)));

// workspace float offsets
#define WS_W    128     // gW [k60][sm55]                 3300
#define WS_Y    17760   // gyhat [o5][s100][i2] float2
#define WS_EM   19776   // gEm [m10][j60] float2
#define WS_TRIG 20992   // 20 dbl sin + 20 dbl cos (ex-gRT region)
#define WS_PACK 21184   // gPack[715] int
#define WS_AP   21952   // A-pack 172032 fp16
#define WS_FH   107968  // gfhat [b512][sm55][i2] float2 = 112640 floats
#define WS_DT   220608  // gDT [p715][k20] = 14300 floats
#define WS_F    234908  // gF 9,830,400 dwords (39.3 MB) B-frag layout

// setup idx ranges (non-overlapping)
#define IX_Y0    3300
#define IX_EM0   4300
#define IX_RT0   4900
#define IX_PACK0 5090
#define IX_AP0   5805
#define IX_DT0   177837   // IX_AP0 + 172032
#define N_SETUP  192137   // + 14300

__device__ __forceinline__ double ipow_d(double x, int e) {
    double r = 1.0;
    for (int i = 0; i < e; ++i) r *= x;
    return r;
}

__device__ double dsmall(int l, int mp, int m, double beta) {
    double fact[20];
    fact[0] = 1.0;
    for (int i = 1; i < 20; ++i) fact[i] = fact[i - 1] * (double)i;
    double cb = cos(0.5 * beta), sb = sin(0.5 * beta);
    double pref = sqrt(fact[l + m] * fact[l - m] * fact[l + mp] * fact[l - mp]);
    int s0 = m - mp; if (s0 < 0) s0 = 0;
    int s1 = l + m;  if (l - mp < s1) s1 = l - mp;
    double tot = 0.0;
    for (int s = s0; s <= s1; ++s) {
        double den = fact[l + m - s] * fact[s] * fact[mp - m + s] * fact[l - mp - s];
        double sgn = ((mp - m + s) & 1) ? -1.0 : 1.0;
        tot += sgn / den * ipow_d(cb, 2 * l + m - mp - 2 * s) * ipow_d(sb, mp - m + 2 * s);
    }
    return pref * tot;
}

extern "C" __global__ void k_setup_w(float* wsf) {
    double* w = (double*)wsf;
    int t = threadIdx.x;
    if (t < 60) {
        double beta = M_PI * (2 * t + 1) / 120.0;
        double sum = 0.0;
        for (int k = 0; k < 30; ++k)
            sum += sin((double)((2 * t + 1) * (2 * k + 1)) * M_PI / 120.0) / (double)(2 * k + 1);
        w[t] = (2.0 / 30.0) * sin(beta) * sum;
    }
    if (t < 20) {   // A-pack trig table: sin/cos(pi*t/10), exact same expr as original
        double ang = M_PI * (double)t / 10.0;
        ((double*)(wsf + WS_TRIG))[t]      = sin(ang);
        ((double*)(wsf + WS_TRIG))[20 + t] = cos(ang);
    }
}

extern "C" __global__ void k_setup_const(float* wsf, const float* __restrict__ kern) {
    const double* w = (const double*)wsf;
    const int tri[11] = {0, 1, 3, 6, 10, 15, 21, 28, 36, 45, 55};
    int idx = blockIdx.x * 64 + threadIdx.x;
    if (idx < IX_Y0) {                      // gW [k][sm]
        int k = idx / 55, smi = idx % 55;
        int l = 0; while (smi >= tri[l + 1]) ++l;
        int m = smi - tri[l];
        double beta = M_PI * (2 * k + 1) / 120.0;
        wsf[WS_W + idx] = (float)(w[k] * dsmall(l, m, 0, beta));
    } else if (idx < IX_EM0) {              // gyhat [o][s][i]
        int i3 = idx - IX_Y0;
        int o = i3 / 200, r5 = i3 % 200;
        int s = r5 / 2, i = r5 % 2;
        int l = 0; while ((l + 1) * (l + 1) <= s) ++l;
        int n = s - l * l - l;
        double dv = dsmall(l, n, 0, M_PI / 160.0);
        const double SC = 1.0 / sqrt(6.0 * 2.0 * 10000.0 / 900.0);
        double ar = 0.0, ai = 0.0;
        for (int g = 0; g < 6; ++g) {
            double kv = (double)kern[i * 30 + o * 6 + g];
            double ang = (double)n * M_PI * (double)g / 3.0;
            ar += kv * cos(ang);
            ai -= kv * sin(ang);
        }
        ((float2*)(wsf + WS_Y))[i3] = make_float2((float)(SC * dv * ar), (float)(SC * dv * ai));
    } else if (idx < IX_RT0) {              // gEm [m][j]
        int t = idx - IX_EM0; int m = t / 60, j = t % 60;
        double a = 2.0 * M_PI * (double)(m * j) / 60.0;
        ((float2*)(wsf + WS_EM))[t] = make_float2((float)cos(a), (float)(-sin(a)));
    } else if (idx < IX_PACK0) {
        // ex-gRT region holds the trig table (written by k_setup_w)
    } else if (idx < IX_AP0) {              // gPack[715]
        int p = idx - IX_PACK0;
        int l = 0, bcur = 0;
        for (;;) { int bs = (l + 1) * (2 * l + 1); if (p < bcur + bs) break; bcur += bs; ++l; }
        int r = p - bcur; int L = 2 * l + 1;
        int m = r / L; int n = r % L - l;
        int smi = tri[l] + m; int sf = l * l + l + n;
        ((int*)(wsf + WS_PACK))[p] = smi * 128 + sf;
    } else if (idx < IX_DT0) {              // A-pack (A-fragment lane order), table lookup
        int ap = idx - IX_AP0;
        int j = ap & 7, lane = (ap >> 3) & 63, tc = ap >> 9;
        int t = tc % 28, c = tc / 28;
        int pq = t * 16 + (lane & 15);
        int kidx = c * 32 + ((lane >> 4) << 3) + j;
        double val = 0.0;
        if (pq < 400 && kidx < 380) {
            int r = kidx >> 1, cpart = kidx & 1;
            int m = r / 19, nn = r % 19, n = nn - 9;
            int p = pq / 20, q = pq % 20;
            int th = ((m * p + n * q) % 20 + 20) % 20;
            double wm = m ? 2.0 : 1.0;
            const double* st = (const double*)(wsf + WS_TRIG);
            val = cpart ? (-wm * st[th]) : (wm * st[20 + th]);
        }
        ((_Float16*)(wsf + WS_AP))[ap] = (_Float16)val;
    } else if (idx < N_SETUP) {             // gDT [p][k] transposed
        int i6 = idx - IX_DT0;
        int p = i6 / 20, k = i6 % 20;
        int l = 0, bcur = 0;
        for (;;) { int bs = (l + 1) * (2 * l + 1); if (p < bcur + bs) break; bcur += bs; ++l; }
        int r = p - bcur; int L = 2 * l + 1;
        int m = r / L; int n = r % L - l;
        double beta = M_PI * (2 * k + 1) / 40.0;
        wsf[WS_DT + i6] = (float)((double)L * dsmall(l, m, n, beta));
    }
}

// ---- fhat: block per (b,i) ----
extern "C" __global__ void __launch_bounds__(256) k_fhat(const float* __restrict__ x,
                                                          float* __restrict__ wsf) {
    __shared__ float  xs[3600];
    __shared__ float2 ems[610];
    __shared__ float2 Y[600];
    int tid = threadIdx.x;
    int bi = blockIdx.x;
    const float4* xp = (const float4*)(x + bi * 3600);
    for (int t = tid; t < 900; t += 256) ((float4*)xs)[t] = xp[t];
    const float2* gEm = (const float2*)(wsf + WS_EM);
    for (int t = tid; t < 600; t += 256) {
        int m = t / 60, j = t - m * 60;
        ems[m * 61 + j] = gEm[t];
    }
    __syncthreads();
    for (int it = tid; it < 600; it += 256) {
        int k = it / 10, m = it - k * 10;
        const float*  row = xs + k * 60;
        const float2* em  = ems + m * 61;
        float ar = 0.f, ai = 0.f;
        #pragma unroll 12
        for (int j = 0; j < 60; ++j) {
            float xv = row[j];
            float2 e = em[j];
            ar += xv * e.x; ai += xv * e.y;
        }
        Y[it] = make_float2(ar, ai);
    }
    __syncthreads();
    if (tid < 55) {
        int smi = tid;
        const int tri[11] = {0, 1, 3, 6, 10, 15, 21, 28, 36, 45, 55};
        int l = 0; while (smi >= tri[l + 1]) ++l;
        int m = smi - tri[l];
        const float* gW = wsf + WS_W;
        float ar = 0.f, ai = 0.f;
        for (int kk = 0; kk < 60; ++kk) {
            float wv = gW[kk * 55 + smi];
            float2 y = Y[kk * 10 + m];
            ar += wv * y.x; ai += wv * y.y;
        }
        int b = bi >> 1, i = bi & 1;
        ((float2*)(wsf + WS_FH))[b * 110 + smi * 2 + i] = make_float2(ar, ai);
    }
}

// unrolled F-sum for compile-time lmin L: steps l = L..9, straight-line,
// all loads independent -> full MLP. z is fp16-packed in LDS.
template<int L>
__device__ __forceinline__ void fsum(int m, int n, int ko, const float* __restrict__ gDT,
                                     const uint32_t* zp, float& fr, float& fi) {
    const int baseL[10] = {0, 1, 7, 22, 50, 95, 161, 252, 372, 525};
    float dv[10 - L];
    uint32_t zv[10 - L];
    #pragma unroll
    for (int l = L; l < 10; ++l) {
        int p = baseL[l] + m * (2 * l + 1) + n + l;
        dv[l - L] = gDT[p * 20 + ko];
        zv[l - L] = zp[p];
    }
    #pragma unroll
    for (int l = L; l < 10; ++l) {
        union { uint32_t u; _Float16 h[2]; } zc; zc.u = zv[l - L];
        fr += dv[l - L] * (float)zc.h[0];
        fi += dv[l - L] * (float)zc.h[1];
    }
}

// ---- k_zF: z (direct-global f/y gather) + quad-store F-phase ----
extern "C" __global__ void __launch_bounds__(256) k_zF(float* __restrict__ wsf) {
    __shared__ uint32_t zsh[2860];    // z [pp4][p715] fp16-packed (11.4 KB)
    int tid = threadIdx.x;
    int half = blockIdx.x & 1;
    int nb   = blockIdx.x >> 1;
    int n0 = nb * 64;
    int PO0 = n0 / 20;

    // ---- z-phase: f/y gathered straight from global (L1/L2-resident) ----
    const float4* gfh4 = (const float4*)(wsf + WS_FH);
    const float4* gy4  = (const float4*)(wsf + WS_Y);
    const int* gPack = (const int*)(wsf + WS_PACK);
    for (int pp = 0; pp < 4; ++pp) {
        int po = PO0 + pp;
        int b = po / 5, o = po % 5;
        const float4* fb = gfh4 + b * 55;
        const float4* yo = gy4 + o * 100;
        for (int p = tid; p < 715; p += 256) {
            int pk = gPack[p];
            float4 f = fb[pk >> 7];
            float4 y = yo[pk & 127];
            float zr = f.x * y.x + f.y * y.y + f.z * y.z + f.w * y.w;
            float zi = f.y * y.x - f.x * y.y + f.w * y.z - f.z * y.w;
            union { _Float16 h[2]; uint32_t u; } cv;
            cv.h[0] = (_Float16)zr; cv.h[1] = (_Float16)zi;
            zsh[pp * 715 + p] = cv.u;
        }
    }
    __syncthreads();

    int col = tid & 63;
    int ko  = (n0 + col) % 20;
    int pp  = ((n0 % 20) + col) / 20;
    int gg  = (n0 >> 4) + (col >> 4);
    int c15 = col & 15;
    const float* gDT = wsf + WS_DT;
    uint4*       gF4 = (uint4*)(wsf + WS_F);
    const uint32_t* zp = zsh + pp * 715;
    // 48 quads of r; even quads -> half 0, odd -> half 1; 24 quads x 64 cols
    for (int it = tid; it < 1536; it += 256) {
        int qj = __builtin_amdgcn_readfirstlane(((it >> 6) << 1) | half);  // quad 0..47
        uint32_t fq[4];
        #pragma unroll
        for (int rr = 0; rr < 4; ++rr) {
            int r = 4 * qj + rr;          // wave-uniform scalar
            float fr = 0.f, fi = 0.f;
            if (r < 190) {
                int m = r / 19;
                int n = r - m * 19 - 9;
                int a = n < 0 ? -n : n;
                int lmin = m > a ? m : a;
                switch (lmin) {
                    case 0: fsum<0>(m, n, ko, gDT, zp, fr, fi); break;
                    case 1: fsum<1>(m, n, ko, gDT, zp, fr, fi); break;
                    case 2: fsum<2>(m, n, ko, gDT, zp, fr, fi); break;
                    case 3: fsum<3>(m, n, ko, gDT, zp, fr, fi); break;
                    case 4: fsum<4>(m, n, ko, gDT, zp, fr, fi); break;
                    case 5: fsum<5>(m, n, ko, gDT, zp, fr, fi); break;
                    case 6: fsum<6>(m, n, ko, gDT, zp, fr, fi); break;
                    case 7: fsum<7>(m, n, ko, gDT, zp, fr, fi); break;
                    case 8: fsum<8>(m, n, ko, gDT, zp, fr, fi); break;
                    default: fsum<9>(m, n, ko, gDT, zp, fr, fi); break;
                }
            }
            union { _Float16 h[2]; uint32_t u; } fv;
            fv.h[0] = (_Float16)fr; fv.h[1] = (_Float16)fi;
            fq[rr] = fv.u;
        }
        // chunk = qj>>2, qp = qj&3; dwords 0..3 = r&3 -> one dense 16B store
        gF4[((qj >> 2) * 3200 + gg) * 64 + (qj & 3) * 16 + c15] =
            make_uint4(fq[0], fq[1], fq[2], fq[3]);
    }
}

// ---- k_gemm2: grid 800, whole 48KB B-slice LDS burst, v7 tile mapping ----
extern "C" __global__ void __launch_bounds__(256) k_gemm2(const float* __restrict__ wsf,
                                                           const float* __restrict__ bias,
                                                           float* __restrict__ out) {
    __shared__ __align__(16) _Float16 Bsh[12 * 4 * 64 * 8];   // 48 KB
    int tid = threadIdx.x;
    int n0 = blockIdx.x * 64;
    int wave = tid >> 6, lane = tid & 63;
    int g0 = n0 >> 4;
    const half8* gA = (const half8*)(wsf + WS_AP);
    const half8* gB = (const half8*)(wsf + WS_F);
    half8* lB = (half8*)Bsh;

    // ---- stage ALL B for this n0 into LDS: 12 frags/wave, loads batched ----
    half8 stg[12];
    #pragma unroll
    for (int i = 0; i < 12; ++i) {
        int cf = wave * 12 + i;                  // cf = c*4 + f, 0..47
        int c = cf >> 2, f = cf & 3;
        stg[i] = gB[(c * 3200 + g0 + f) * 64 + lane];
    }
    #pragma unroll
    for (int i = 0; i < 12; ++i)
        lB[(wave * 12 + i) * 64 + lane] = stg[i];

    int t0 = wave * 7;
    int ntile = (wave < 3) ? 7 : 4;          // tiles 21..24 real; 25..27 pad

    f32x4 acc[7][4];
    #pragma unroll
    for (int tt = 0; tt < 7; ++tt)
        #pragma unroll
        for (int f = 0; f < 4; ++f) acc[tt][f] = (f32x4){0.f, 0.f, 0.f, 0.f};

    half8 bufA[2][7];
    #pragma unroll
    for (int tt = 0; tt < 7; ++tt)
        if (tt < ntile) bufA[0][tt] = gA[(t0 + tt) * 64 + lane];

    __syncthreads();   // B resident in LDS

    #pragma unroll
    for (int c = 0; c < 12; ++c) {
        const int cur = c & 1, nxt = cur ^ 1;
        if (c < 11) {
            #pragma unroll
            for (int tt = 0; tt < 7; ++tt)
                if (tt < ntile) bufA[nxt][tt] = gA[((c + 1) * 28 + t0 + tt) * 64 + lane];
        }
        half8 bB[4];
        #pragma unroll
        for (int f = 0; f < 4; ++f) bB[f] = lB[(c * 4 + f) * 64 + lane];
        #pragma unroll
        for (int tt = 0; tt < 7; ++tt) {
            if (tt < ntile) {
                #pragma unroll
                for (int f = 0; f < 4; ++f)
                    acc[tt][f] = __builtin_amdgcn_mfma_f32_16x16x32_f16(bufA[cur][tt], bB[f], acc[tt][f], 0, 0, 0);
            }
        }
    }

    int quad4 = (lane >> 4) << 2, col15 = lane & 15;
    float bo_f[4];
    #pragma unroll
    for (int f = 0; f < 4; ++f) bo_f[f] = bias[((n0 + f * 16 + col15) / 20) % 5];
    #pragma unroll
    for (int tt = 0; tt < 7; ++tt) {
        if (tt < ntile) {
            int pqb = (t0 + tt) * 16 + quad4;
            #pragma unroll
            for (int f = 0; f < 4; ++f) {
                int n = n0 + f * 16 + col15;
                float bo = bo_f[f];
                float4 v = make_float4(acc[tt][f].x + bo, acc[tt][f].y + bo,
                                       acc[tt][f].z + bo, acc[tt][f].w + bo);
                *(float4*)(out + n * 400 + pqb) = v;
            }
        }
    }
}

extern "C" void kernel_launch(void* const* d_in, const int* in_sizes, int n_in,
                              void* d_out, int out_size, void* d_ws, size_t ws_size,
                              hipStream_t stream) {
    const float* x    = (const float*)d_in[0];
    const float* kern = (const float*)d_in[1];
    const float* bias = (const float*)d_in[2];
    float* out = (float*)d_out;
    float* wsf = (float*)d_ws;
    k_setup_w    <<<1,    64,  0, stream>>>(wsf);
    k_setup_const<<<3003, 64,  0, stream>>>(wsf, kern);
    k_fhat       <<<1024, 256, 0, stream>>>(x, wsf);
    k_zF         <<<1600, 256, 0, stream>>>(wsf);
    k_gemm2      <<<800,  256, 0, stream>>>(wsf, bias, out);
}

// Round 15
// 173.203 us; speedup vs baseline: 1.0443x; 1.0251x over previous
//
#include <hip/hip_runtime.h>
#include <math.h>
#include <stdint.h>

// ---------------------------------------------------------------------------
// v16: v13 base (best measured, 174.3us; v15's direct-global z reverted) +
//  - k_zF: ONE 512-thread block per n0 (grid 800). Same total waves as the
//    1600x256 r-split, but z-phase computed ONCE per n0 (was duplicated in
//    each block pair). F-phase: 8 waves x 6 quads. Bit-identical.
//  - k_gemm2: split-stage B pipeline: stage chunks 0..5 -> issue 6..11 loads
//    to regs -> barrier -> compute c=0..5 (MFMA hides in-flight loads) ->
//    ds_write 6..11 -> barrier -> compute c=6..11. Exposed burst latency
//    drops to one ds_write+barrier; -24 VGPR. Same math order.
// Pipeline: setup_w -> setup_const -> fhat -> zF -> gemm2.
// ---------------------------------------------------------------------------

typedef _Float16 half8 __attribute__((ext_vector_type(8)));
typedef float    f32x4 __attribute__((ext_vector_type(4)));

// workspace float offsets
#define WS_W    128     // gW [k60][sm55]                 3300
#define WS_Y    17760   // gyhat [o5][s100][i2] float2
#define WS_EM   19776   // gEm [m10][j60] float2
#define WS_TRIG 20992   // 20 dbl sin + 20 dbl cos (ex-gRT region)
#define WS_PACK 21184   // gPack[715] int
#define WS_AP   21952   // A-pack 172032 fp16
#define WS_FH   107968  // gfhat [b512][sm55][i2] float2 = 112640 floats
#define WS_DT   220608  // gDT [p715][k20] = 14300 floats
#define WS_F    234908  // gF 9,830,400 dwords (39.3 MB) B-frag layout

// setup idx ranges (non-overlapping)
#define IX_Y0    3300
#define IX_EM0   4300
#define IX_RT0   4900
#define IX_PACK0 5090
#define IX_AP0   5805
#define IX_DT0   177837   // IX_AP0 + 172032
#define N_SETUP  192137   // + 14300

__device__ __forceinline__ double ipow_d(double x, int e) {
    double r = 1.0;
    for (int i = 0; i < e; ++i) r *= x;
    return r;
}

__device__ double dsmall(int l, int mp, int m, double beta) {
    double fact[20];
    fact[0] = 1.0;
    for (int i = 1; i < 20; ++i) fact[i] = fact[i - 1] * (double)i;
    double cb = cos(0.5 * beta), sb = sin(0.5 * beta);
    double pref = sqrt(fact[l + m] * fact[l - m] * fact[l + mp] * fact[l - mp]);
    int s0 = m - mp; if (s0 < 0) s0 = 0;
    int s1 = l + m;  if (l - mp < s1) s1 = l - mp;
    double tot = 0.0;
    for (int s = s0; s <= s1; ++s) {
        double den = fact[l + m - s] * fact[s] * fact[mp - m + s] * fact[l - mp - s];
        double sgn = ((mp - m + s) & 1) ? -1.0 : 1.0;
        tot += sgn / den * ipow_d(cb, 2 * l + m - mp - 2 * s) * ipow_d(sb, mp - m + 2 * s);
    }
    return pref * tot;
}

extern "C" __global__ void k_setup_w(float* wsf) {
    double* w = (double*)wsf;
    int t = threadIdx.x;
    if (t < 60) {
        double beta = M_PI * (2 * t + 1) / 120.0;
        double sum = 0.0;
        for (int k = 0; k < 30; ++k)
            sum += sin((double)((2 * t + 1) * (2 * k + 1)) * M_PI / 120.0) / (double)(2 * k + 1);
        w[t] = (2.0 / 30.0) * sin(beta) * sum;
    }
    if (t < 20) {   // A-pack trig table: sin/cos(pi*t/10), exact same expr as original
        double ang = M_PI * (double)t / 10.0;
        ((double*)(wsf + WS_TRIG))[t]      = sin(ang);
        ((double*)(wsf + WS_TRIG))[20 + t] = cos(ang);
    }
}

extern "C" __global__ void k_setup_const(float* wsf, const float* __restrict__ kern) {
    const double* w = (const double*)wsf;
    const int tri[11] = {0, 1, 3, 6, 10, 15, 21, 28, 36, 45, 55};
    int idx = blockIdx.x * 64 + threadIdx.x;
    if (idx < IX_Y0) {                      // gW [k][sm]
        int k = idx / 55, smi = idx % 55;
        int l = 0; while (smi >= tri[l + 1]) ++l;
        int m = smi - tri[l];
        double beta = M_PI * (2 * k + 1) / 120.0;
        wsf[WS_W + idx] = (float)(w[k] * dsmall(l, m, 0, beta));
    } else if (idx < IX_EM0) {              // gyhat [o][s][i]
        int i3 = idx - IX_Y0;
        int o = i3 / 200, r5 = i3 % 200;
        int s = r5 / 2, i = r5 % 2;
        int l = 0; while ((l + 1) * (l + 1) <= s) ++l;
        int n = s - l * l - l;
        double dv = dsmall(l, n, 0, M_PI / 160.0);
        const double SC = 1.0 / sqrt(6.0 * 2.0 * 10000.0 / 900.0);
        double ar = 0.0, ai = 0.0;
        for (int g = 0; g < 6; ++g) {
            double kv = (double)kern[i * 30 + o * 6 + g];
            double ang = (double)n * M_PI * (double)g / 3.0;
            ar += kv * cos(ang);
            ai -= kv * sin(ang);
        }
        ((float2*)(wsf + WS_Y))[i3] = make_float2((float)(SC * dv * ar), (float)(SC * dv * ai));
    } else if (idx < IX_RT0) {              // gEm [m][j]
        int t = idx - IX_EM0; int m = t / 60, j = t % 60;
        double a = 2.0 * M_PI * (double)(m * j) / 60.0;
        ((float2*)(wsf + WS_EM))[t] = make_float2((float)cos(a), (float)(-sin(a)));
    } else if (idx < IX_PACK0) {
        // ex-gRT region holds the trig table (written by k_setup_w)
    } else if (idx < IX_AP0) {              // gPack[715]
        int p = idx - IX_PACK0;
        int l = 0, bcur = 0;
        for (;;) { int bs = (l + 1) * (2 * l + 1); if (p < bcur + bs) break; bcur += bs; ++l; }
        int r = p - bcur; int L = 2 * l + 1;
        int m = r / L; int n = r % L - l;
        int smi = tri[l] + m; int sf = l * l + l + n;
        ((int*)(wsf + WS_PACK))[p] = smi * 128 + sf;
    } else if (idx < IX_DT0) {              // A-pack (A-fragment lane order), table lookup
        int ap = idx - IX_AP0;
        int j = ap & 7, lane = (ap >> 3) & 63, tc = ap >> 9;
        int t = tc % 28, c = tc / 28;
        int pq = t * 16 + (lane & 15);
        int kidx = c * 32 + ((lane >> 4) << 3) + j;
        double val = 0.0;
        if (pq < 400 && kidx < 380) {
            int r = kidx >> 1, cpart = kidx & 1;
            int m = r / 19, nn = r % 19, n = nn - 9;
            int p = pq / 20, q = pq % 20;
            int th = ((m * p + n * q) % 20 + 20) % 20;
            double wm = m ? 2.0 : 1.0;
            const double* st = (const double*)(wsf + WS_TRIG);
            val = cpart ? (-wm * st[th]) : (wm * st[20 + th]);
        }
        ((_Float16*)(wsf + WS_AP))[ap] = (_Float16)val;
    } else if (idx < N_SETUP) {             // gDT [p][k] transposed
        int i6 = idx - IX_DT0;
        int p = i6 / 20, k = i6 % 20;
        int l = 0, bcur = 0;
        for (;;) { int bs = (l + 1) * (2 * l + 1); if (p < bcur + bs) break; bcur += bs; ++l; }
        int r = p - bcur; int L = 2 * l + 1;
        int m = r / L; int n = r % L - l;
        double beta = M_PI * (2 * k + 1) / 40.0;
        wsf[WS_DT + i6] = (float)((double)L * dsmall(l, m, n, beta));
    }
}

// ---- fhat: block per (b,i) ----
extern "C" __global__ void __launch_bounds__(256) k_fhat(const float* __restrict__ x,
                                                          float* __restrict__ wsf) {
    __shared__ float  xs[3600];
    __shared__ float2 ems[610];
    __shared__ float2 Y[600];
    int tid = threadIdx.x;
    int bi = blockIdx.x;
    const float4* xp = (const float4*)(x + bi * 3600);
    for (int t = tid; t < 900; t += 256) ((float4*)xs)[t] = xp[t];
    const float2* gEm = (const float2*)(wsf + WS_EM);
    for (int t = tid; t < 600; t += 256) {
        int m = t / 60, j = t - m * 60;
        ems[m * 61 + j] = gEm[t];
    }
    __syncthreads();
    for (int it = tid; it < 600; it += 256) {
        int k = it / 10, m = it - k * 10;
        const float*  row = xs + k * 60;
        const float2* em  = ems + m * 61;
        float ar = 0.f, ai = 0.f;
        #pragma unroll 12
        for (int j = 0; j < 60; ++j) {
            float xv = row[j];
            float2 e = em[j];
            ar += xv * e.x; ai += xv * e.y;
        }
        Y[it] = make_float2(ar, ai);
    }
    __syncthreads();
    if (tid < 55) {
        int smi = tid;
        const int tri[11] = {0, 1, 3, 6, 10, 15, 21, 28, 36, 45, 55};
        int l = 0; while (smi >= tri[l + 1]) ++l;
        int m = smi - tri[l];
        const float* gW = wsf + WS_W;
        float ar = 0.f, ai = 0.f;
        for (int kk = 0; kk < 60; ++kk) {
            float wv = gW[kk * 55 + smi];
            float2 y = Y[kk * 10 + m];
            ar += wv * y.x; ai += wv * y.y;
        }
        int b = bi >> 1, i = bi & 1;
        ((float2*)(wsf + WS_FH))[b * 110 + smi * 2 + i] = make_float2(ar, ai);
    }
}

// unrolled F-sum for compile-time lmin L: steps l = L..9, straight-line,
// all loads independent -> full MLP. z is fp16-packed in LDS.
template<int L>
__device__ __forceinline__ void fsum(int m, int n, int ko, const float* __restrict__ gDT,
                                     const uint32_t* zp, float& fr, float& fi) {
    const int baseL[10] = {0, 1, 7, 22, 50, 95, 161, 252, 372, 525};
    float dv[10 - L];
    uint32_t zv[10 - L];
    #pragma unroll
    for (int l = L; l < 10; ++l) {
        int p = baseL[l] + m * (2 * l + 1) + n + l;
        dv[l - L] = gDT[p * 20 + ko];
        zv[l - L] = zp[p];
    }
    #pragma unroll
    for (int l = L; l < 10; ++l) {
        union { uint32_t u; _Float16 h[2]; } zc; zc.u = zv[l - L];
        fr += dv[l - L] * (float)zc.h[0];
        fi += dv[l - L] * (float)zc.h[1];
    }
}

// ---- k_zF: 512 threads/block, grid 800. z once per n0; F: 8 waves x 6 quads ----
extern "C" __global__ void __launch_bounds__(512) k_zF(float* __restrict__ wsf) {
    __shared__ uint32_t zsh[2860];    // z [pp4][p715] fp16-packed (11.4 KB)
    __shared__ float4 fbl4[110];
    __shared__ float4 yol4[500];
    int tid = threadIdx.x;
    int n0 = blockIdx.x * 64;
    int PO0 = n0 / 20;
    int bf = PO0 / 5;

    const float4* gfh4 = (const float4*)(wsf + WS_FH);
    for (int t = tid; t < 110; t += 512) {
        int bsel = t / 55, i55 = t - bsel * 55;
        int b = bf + bsel;
        fbl4[t] = (b < 512) ? gfh4[b * 55 + i55] : make_float4(0.f, 0.f, 0.f, 0.f);
    }
    for (int t = tid; t < 500; t += 512) yol4[t] = ((const float4*)(wsf + WS_Y))[t];
    __syncthreads();
    const int* gPack = (const int*)(wsf + WS_PACK);
    for (int pp = 0; pp < 4; ++pp) {
        int po = PO0 + pp;
        int b_loc = po / 5 - bf, o = po % 5;
        for (int p = tid; p < 715; p += 512) {
            int pk = gPack[p];
            int smi = pk >> 7, sf = pk & 127;
            float4 f = fbl4[b_loc * 55 + smi];
            float4 y = yol4[o * 100 + sf];
            float zr = f.x * y.x + f.y * y.y + f.z * y.z + f.w * y.w;
            float zi = f.y * y.x - f.x * y.y + f.w * y.z - f.z * y.w;
            union { _Float16 h[2]; uint32_t u; } cv;
            cv.h[0] = (_Float16)zr; cv.h[1] = (_Float16)zi;
            zsh[pp * 715 + p] = cv.u;
        }
    }
    __syncthreads();

    int col = tid & 63;
    int ko  = (n0 + col) % 20;
    int pp  = ((n0 % 20) + col) / 20;
    int gg  = (n0 >> 4) + (col >> 4);
    int c15 = col & 15;
    const float* gDT = wsf + WS_DT;
    uint4*       gF4 = (uint4*)(wsf + WS_F);
    const uint32_t* zp = zsh + pp * 715;
    // 48 quads x 64 cols = 3072 items; wave w handles qj in {w, w+8, ...}
    for (int it = tid; it < 3072; it += 512) {
        int qj = __builtin_amdgcn_readfirstlane(it >> 6);  // wave-uniform quad 0..47
        uint32_t fq[4];
        #pragma unroll
        for (int rr = 0; rr < 4; ++rr) {
            int r = 4 * qj + rr;          // wave-uniform scalar
            float fr = 0.f, fi = 0.f;
            if (r < 190) {
                int m = r / 19;
                int n = r - m * 19 - 9;
                int a = n < 0 ? -n : n;
                int lmin = m > a ? m : a;
                switch (lmin) {
                    case 0: fsum<0>(m, n, ko, gDT, zp, fr, fi); break;
                    case 1: fsum<1>(m, n, ko, gDT, zp, fr, fi); break;
                    case 2: fsum<2>(m, n, ko, gDT, zp, fr, fi); break;
                    case 3: fsum<3>(m, n, ko, gDT, zp, fr, fi); break;
                    case 4: fsum<4>(m, n, ko, gDT, zp, fr, fi); break;
                    case 5: fsum<5>(m, n, ko, gDT, zp, fr, fi); break;
                    case 6: fsum<6>(m, n, ko, gDT, zp, fr, fi); break;
                    case 7: fsum<7>(m, n, ko, gDT, zp, fr, fi); break;
                    case 8: fsum<8>(m, n, ko, gDT, zp, fr, fi); break;
                    default: fsum<9>(m, n, ko, gDT, zp, fr, fi); break;
                }
            }
            union { _Float16 h[2]; uint32_t u; } fv;
            fv.h[0] = (_Float16)fr; fv.h[1] = (_Float16)fi;
            fq[rr] = fv.u;
        }
        // chunk = qj>>2, qp = qj&3; dwords 0..3 = r&3 -> one dense 16B store
        gF4[((qj >> 2) * 3200 + gg) * 64 + (qj & 3) * 16 + c15] =
            make_uint4(fq[0], fq[1], fq[2], fq[3]);
    }
}

// ---- k_gemm2: grid 800, split-stage B pipeline (6+6 chunks), v7 tiles ----
extern "C" __global__ void __launch_bounds__(256) k_gemm2(const float* __restrict__ wsf,
                                                           const float* __restrict__ bias,
                                                           float* __restrict__ out) {
    __shared__ __align__(16) _Float16 Bsh[12 * 4 * 64 * 8];   // 48 KB
    int tid = threadIdx.x;
    int n0 = blockIdx.x * 64;
    int wave = tid >> 6, lane = tid & 63;
    int g0 = n0 >> 4;
    const half8* gA = (const half8*)(wsf + WS_AP);
    const half8* gB = (const half8*)(wsf + WS_F);
    half8* lB = (half8*)Bsh;

    // stage chunks 0..5 (24 frag-rows): 6 frags/wave
    half8 stg[6];
    #pragma unroll
    for (int i = 0; i < 6; ++i) {
        int cf = wave * 6 + i;                  // 0..23 = c*4+f, c<6
        int c = cf >> 2, f = cf & 3;
        stg[i] = gB[(c * 3200 + g0 + f) * 64 + lane];
    }
    #pragma unroll
    for (int i = 0; i < 6; ++i)
        lB[(wave * 6 + i) * 64 + lane] = stg[i];

    // issue chunks 6..11 loads (stay in flight under first-half compute)
    half8 stg2[6];
    #pragma unroll
    for (int i = 0; i < 6; ++i) {
        int cf = 24 + wave * 6 + i;             // 24..47 = c*4+f, c>=6
        int c = cf >> 2, f = cf & 3;
        stg2[i] = gB[(c * 3200 + g0 + f) * 64 + lane];
    }

    int t0 = wave * 7;
    int ntile = (wave < 3) ? 7 : 4;          // tiles 21..24 real; 25..27 pad

    f32x4 acc[7][4];
    #pragma unroll
    for (int tt = 0; tt < 7; ++tt)
        #pragma unroll
        for (int f = 0; f < 4; ++f) acc[tt][f] = (f32x4){0.f, 0.f, 0.f, 0.f};

    half8 bufA[2][7];
    #pragma unroll
    for (int tt = 0; tt < 7; ++tt)
        if (tt < ntile) bufA[0][tt] = gA[(t0 + tt) * 64 + lane];

    __syncthreads();   // chunks 0..5 resident in LDS

    #pragma unroll
    for (int c = 0; c < 12; ++c) {
        if (c == 6) {   // second half: write staged regs, then barrier
            #pragma unroll
            for (int i = 0; i < 6; ++i)
                lB[(24 + wave * 6 + i) * 64 + lane] = stg2[i];
            __syncthreads();
        }
        const int cur = c & 1, nxt = cur ^ 1;
        if (c < 11) {
            #pragma unroll
            for (int tt = 0; tt < 7; ++tt)
                if (tt < ntile) bufA[nxt][tt] = gA[((c + 1) * 28 + t0 + tt) * 64 + lane];
        }
        half8 bB[4];
        #pragma unroll
        for (int f = 0; f < 4; ++f) bB[f] = lB[(c * 4 + f) * 64 + lane];
        #pragma unroll
        for (int tt = 0; tt < 7; ++tt) {
            if (tt < ntile) {
                #pragma unroll
                for (int f = 0; f < 4; ++f)
                    acc[tt][f] = __builtin_amdgcn_mfma_f32_16x16x32_f16(bufA[cur][tt], bB[f], acc[tt][f], 0, 0, 0);
            }
        }
    }

    int quad4 = (lane >> 4) << 2, col15 = lane & 15;
    float bo_f[4];
    #pragma unroll
    for (int f = 0; f < 4; ++f) bo_f[f] = bias[((n0 + f * 16 + col15) / 20) % 5];
    #pragma unroll
    for (int tt = 0; tt < 7; ++tt) {
        if (tt < ntile) {
            int pqb = (t0 + tt) * 16 + quad4;
            #pragma unroll
            for (int f = 0; f < 4; ++f) {
                int n = n0 + f * 16 + col15;
                float bo = bo_f[f];
                float4 v = make_float4(acc[tt][f].x + bo, acc[tt][f].y + bo,
                                       acc[tt][f].z + bo, acc[tt][f].w + bo);
                *(float4*)(out + n * 400 + pqb) = v;
            }
        }
    }
}

extern "C" void kernel_launch(void* const* d_in, const int* in_sizes, int n_in,
                              void* d_out, int out_size, void* d_ws, size_t ws_size,
                              hipStream_t stream) {
    const float* x    = (const float*)d_in[0];
    const float* kern = (const float*)d_in[1];
    const float* bias = (const float*)d_in[2];
    float* out = (float*)d_out;
    float* wsf = (float*)d_ws;
    k_setup_w    <<<1,    64,  0, stream>>>(wsf);
    k_setup_const<<<3003, 64,  0, stream>>>(wsf, kern);
    k_fhat       <<<1024, 256, 0, stream>>>(x, wsf);
    k_zF         <<<800,  512, 0, stream>>>(wsf);
    k_gemm2      <<<800,  256, 0, stream>>>(wsf, bias, out);
}